// Round 7
// baseline (238.543 us; speedup 1.0000x reference)
//
#include <hip/hip_runtime.h>
#include <cstdint>
#include <cstddef>

typedef __bf16 bf16x8 __attribute__((ext_vector_type(8)));
typedef float f32x4 __attribute__((ext_vector_type(4)));
typedef float f32x16 __attribute__((ext_vector_type(16)));
typedef unsigned short u16;
typedef unsigned int u32;

static constexpr int Bn = 2;       // batch
static constexpr int L  = 2048;    // sequence
static constexpr int Dm = 1024;    // model dim
static constexpr int H  = 16;      // heads
static constexpr int DH = 64;      // head dim
static constexpr int M  = Bn * L;  // 4096 rows
static constexpr size_t PER = (size_t)Bn * H * L * DH;   // 4M elems
static constexpr int NQ = Bn * H * L;                    // 65536 q rows

#define SC 0.18033688f   /* 0.125 * log2(e): folded into Q so QK^T is in exp2 domain */

__device__ __forceinline__ u16 f2bf(float f) {
    union { float f; u32 u; } v; v.f = f;
    u32 u = v.u + 0x7FFFu + ((v.u >> 16) & 1u);   // RNE
    return (u16)(u >> 16);
}

// packed f32x2 -> bf16x2 (low = a). HW v_cvt_pk_bf16_f32 on gfx950.
__device__ __forceinline__ u32 pk_bf16(float a, float b) {
#if __has_builtin(__builtin_amdgcn_cvt_pk_bf16_f32)
    typedef __bf16 bf16x2_t __attribute__((ext_vector_type(2)));
    bf16x2_t t = __builtin_amdgcn_cvt_pk_bf16_f32(a, b);
    u32 r; __builtin_memcpy(&r, &t, 4); return r;
#else
    return (u32)f2bf(a) | ((u32)f2bf(b) << 16);
#endif
}
__device__ __forceinline__ u16 f2bf1(float f) { return (u16)(pk_bf16(f, f) & 0xffffu); }

// async global->LDS, 16B per lane; LDS dest = wave-uniform base + lane*16
__device__ __forceinline__ void gl2lds16(const void* g, void* l) {
    __builtin_amdgcn_global_load_lds(
        (const __attribute__((address_space(1))) u32*)(uintptr_t)g,
        (__attribute__((address_space(3))) u32*)(uintptr_t)l, 16, 0, 0);
}

// ---------------------------------------------------------------------------
// convert_in: fp32 -> bf16, flat copy of q,k,v (blockIdx.y selects tensor)
// ---------------------------------------------------------------------------
__global__ __launch_bounds__(256) void convert_in(
    const float* __restrict__ q, const float* __restrict__ k, const float* __restrict__ v,
    u16* __restrict__ dst)
{
    const float* src = (blockIdx.y == 0) ? q : (blockIdx.y == 1) ? k : v;
    u16* d = dst + (size_t)blockIdx.y * M * Dm;
    const size_t t = (size_t)blockIdx.x * 256 + threadIdx.x;
    const float4* s4 = reinterpret_cast<const float4*>(src) + t * 2;
    float4 f0 = s4[0], f1 = s4[1];
    u32 o[4] = { pk_bf16(f0.x, f0.y), pk_bf16(f0.z, f0.w),
                 pk_bf16(f1.x, f1.y), pk_bf16(f1.z, f1.w) };
    reinterpret_cast<uint4*>(d)[t] = *reinterpret_cast<uint4*>(o);
}

// ---------------------------------------------------------------------------
// convert_wt: fp32 W [K][N] -> bf16 W^T [N][K], 64x64 LDS tile. z selects W.
// ---------------------------------------------------------------------------
__global__ __launch_bounds__(256) void convert_wt(
    const float* __restrict__ Wq, const float* __restrict__ Wk,
    const float* __restrict__ Wv, const float* __restrict__ Wo,
    u16* __restrict__ dst)
{
    __shared__ u16 Ts[64][72];
    const int z = blockIdx.z;
    const float* W = (z == 0) ? Wq : (z == 1) ? Wk : (z == 2) ? Wv : Wo;
    u16* o = dst + (size_t)z * Dm * Dm;
    const int n0 = blockIdx.x * 64, k0 = blockIdx.y * 64;
    const int tid = threadIdx.x;

    {
        const int kr = tid >> 2, nc = (tid & 3) * 16;
        const float* s = W + (size_t)(k0 + kr) * Dm + n0 + nc;
        const float4* s4 = reinterpret_cast<const float4*>(s);
        float4 a = s4[0], b = s4[1], c = s4[2], d = s4[3];
        u32 t[8] = { pk_bf16(a.x, a.y), pk_bf16(a.z, a.w), pk_bf16(b.x, b.y), pk_bf16(b.z, b.w),
                     pk_bf16(c.x, c.y), pk_bf16(c.z, c.w), pk_bf16(d.x, d.y), pk_bf16(d.z, d.w) };
        *reinterpret_cast<uint4*>(&Ts[kr][nc])     = reinterpret_cast<uint4*>(t)[0];
        *reinterpret_cast<uint4*>(&Ts[kr][nc + 8]) = reinterpret_cast<uint4*>(t)[1];
    }
    __syncthreads();
    {
        const int nr = tid >> 2, kc = (tid & 3) * 16;
        u16 w[16];
        #pragma unroll
        for (int j = 0; j < 16; ++j) w[j] = Ts[kc + j][nr];
        u16* dptr = o + (size_t)(n0 + nr) * Dm + k0 + kc;
        *reinterpret_cast<uint4*>(dptr)     = reinterpret_cast<uint4*>(w)[0];
        *reinterpret_cast<uint4*>(dptr + 8) = reinterpret_cast<uint4*>(w)[1];
    }
}

// ---------------------------------------------------------------------------
// gemm_qkv: 128x128 tile, BK=32, dbuf single-barrier K-loop.
// Epilogue: per-wave LDS C-tile staging -> fully-coalesced 1KB stores.
// z==2 stages the tile transposed and stores V^T [B,H,DH,L] directly.
// ---------------------------------------------------------------------------
__global__ __launch_bounds__(256) void gemm_qkv(
    const u16* __restrict__ Abuf, const u16* __restrict__ Wtb,
    const float* __restrict__ bq, const float* __restrict__ bk, const float* __restrict__ bv,
    u16* __restrict__ Qh, u16* __restrict__ Kh, u16* __restrict__ Vth)
{
    __shared__ __align__(16) char smem[36864];   // main: As0/As1 @0/8192, Bs0/Bs1 @16384/24576; epi: 4x9216B

    const int tid = threadIdx.x;
    const int wave = tid >> 6, lane = tid & 63;
    const int quad = lane >> 4, l16 = lane & 15;
    const int wr = wave >> 1, wc = wave & 1;
    const int z = blockIdx.z;
    const u16* A  = Abuf + (size_t)z * M * Dm;
    const u16* Bt = Wtb  + (size_t)z * Dm * Dm;
    const float* bias = (z == 0) ? bq : (z == 1) ? bk : bv;
    u16* out = (z == 0) ? Qh : (z == 1) ? Kh : Vth;
    const int n0 = blockIdx.x * 128, m0 = blockIdx.y * 128;

    const int srow = lane >> 2;
    const int skc  = (lane & 3) * 8;

    f32x4 acc[4][4] = {};

    auto stage = [&](int k0, int bi) {
        #pragma unroll
        for (int i = 0; i < 2; ++i) {
            const int ra = i * 64 + wave * 16;
            gl2lds16(A  + (size_t)(m0 + ra + srow) * Dm + k0 + skc, smem + bi * 8192 + ra * 64);
            gl2lds16(Bt + (size_t)(n0 + ra + srow) * Dm + k0 + skc, smem + 16384 + bi * 8192 + ra * 64);
        }
    };

    stage(0, 0);
    for (int k0 = 0, it = 0; k0 < Dm; k0 += 32, ++it) {
        const int cb = it & 1;
        __syncthreads();
        if (k0 + 32 < Dm) stage(k0 + 32, cb ^ 1);
        const u16* Asb = (const u16*)(smem + cb * 8192);
        const u16* Bsb = (const u16*)(smem + 16384 + cb * 8192);
        bf16x8 af[4], bf[4];
        #pragma unroll
        for (int t = 0; t < 4; ++t) {
            af[t] = *reinterpret_cast<const bf16x8*>(&Asb[(wr * 64 + t * 16 + l16) * 32 + quad * 8]);
            bf[t] = *reinterpret_cast<const bf16x8*>(&Bsb[(wc * 64 + t * 16 + l16) * 32 + quad * 8]);
        }
        #pragma unroll
        for (int mt = 0; mt < 4; ++mt)
            #pragma unroll
            for (int nt = 0; nt < 4; ++nt)
                acc[mt][nt] = __builtin_amdgcn_mfma_f32_16x16x32_bf16(af[mt], bf[nt], acc[mt][nt], 0, 0, 0);
    }

    // ---- epilogue: C tile -> per-wave LDS [64][72] -> coalesced stores ----
    __syncthreads();   // all main-loop LDS reads done before overlay
    u16* tile = (u16*)smem + wave * 4608;        // 64*72 u16 = 9216B per wave
    const float qscale = (z == 0) ? SC : 1.0f;
    #pragma unroll
    for (int nt = 0; nt < 4; ++nt) {
        const int n = n0 + wc * 64 + nt * 16 + l16;
        const float badd = bias[n];
        const int cc = nt * 16 + l16;
        #pragma unroll
        for (int mt = 0; mt < 4; ++mt) {
            #pragma unroll
            for (int r = 0; r < 4; ++r) {
                const int rr = mt * 16 + quad * 4 + r;
                const u16 vv = f2bf1((acc[mt][nt][r] + badd) * qscale);
                if (z == 2) tile[cc * 72 + rr] = vv;   // transposed: [d][ll]
                else        tile[rr * 72 + cc] = vv;   // [ll][d]
            }
        }
    }
    __syncthreads();

    const int rsub = lane >> 3;          // 0..7
    const int csub = (lane & 7) * 8;     // u16 col offset (16B)
    const int h2 = (n0 + wc * 64) >> 6;
    const int mb = m0 + wr * 64;
    const int bb = mb >> 11, ll0 = mb & 2047;
    if (z == 2) {
        const size_t baseV = ((size_t)(bb * H + h2)) * DH * L;
        #pragma unroll
        for (int j = 0; j < 8; ++j) {
            const int d = j * 8 + rsub;
            uint4 vv = *reinterpret_cast<const uint4*>(&tile[d * 72 + csub]);
            *reinterpret_cast<uint4*>(out + baseV + (size_t)d * L + ll0 + csub) = vv;
        }
    } else {
        const size_t base = ((size_t)(bb * H + h2)) * L * DH;
        #pragma unroll
        for (int j = 0; j < 8; ++j) {
            const int row = j * 8 + rsub;
            uint4 vv = *reinterpret_cast<const uint4*>(&tile[row * 72 + csub]);
            *reinterpret_cast<uint4*>(out + base + (size_t)(ll0 + row) * DH + csub) = vv;
        }
    }
}

// ---------------------------------------------------------------------------
// attn v6: k-split x2 across blocks (blockIdx.x = qt*2+half; each block does
// 16 K-tiles). Writes UNNORMALIZED partial O (bf16) + partial rsum (f32);
// attn_merge normalizes. Core math = R3/R5 (S^T = K@Q^T, O^T = V^T@P^T,
// 32x32x16 MFMA, in-register P^T via v_permlane32_swap_b32, dbuf staging).
// ---------------------------------------------------------------------------
__global__ __launch_bounds__(256) void attn(
    const u16* __restrict__ Qh, const u16* __restrict__ Kh,
    const u16* __restrict__ Vth, u16* __restrict__ Opart, float* __restrict__ rsums)
{
    __shared__ __align__(16) char smem[32768];   // 2 x (K 8KB + V 8KB); Os overlays buf0
    u16* Os = (u16*)smem;

    const int tid  = threadIdx.x;
    const int wave = tid >> 6, lane = tid & 63;
    const int l31  = lane & 31, hh = lane >> 5;
    const int qt = blockIdx.x >> 1, half = blockIdx.x & 1;
    const int h = blockIdx.y, b = blockIdx.z;
    const size_t hb = ((size_t)(b * H + h)) * L * DH;
    const int q0 = qt * 128 + wave * 32;

    u16*  Op = Opart + (size_t)half * PER;
    float* rp = rsums + (size_t)half * NQ;

    // Q fragments (B operand), in regs
    bf16x8 qf[4];
    {
        const u16* qp = Qh + hb + (size_t)(q0 + l31) * DH + hh * 8;
        #pragma unroll
        for (int c = 0; c < 4; ++c)
            qf[c] = *reinterpret_cast<const bf16x8*>(qp + c * 16);
    }

    const int r_off = lane >> 3;
    const int s_sl  = lane & 7;

    auto stage = [&](int kt, int bi) {
        char* base = smem + bi * 16384;
        #pragma unroll
        for (int i = 0; i < 2; ++i) {
            const int rr = wave * 16 + i * 8 + r_off;
            gl2lds16(Kh  + hb + (size_t)(kt * 64 + rr) * DH + ((s_sl ^ (rr & 7)) << 3),
                     base + (wave * 16 + i * 8) * 128);
            gl2lds16(Vth + hb + (size_t)rr * L + kt * 64 + ((s_sl ^ (rr & 7)) << 3),
                     base + 8192 + (wave * 16 + i * 8) * 128);
        }
    };

    int vbK[2], vbV[2];
    #pragma unroll
    for (int t = 0; t < 2; ++t) {
        const int rr = t * 32 + l31;
        vbK[t] = rr * 128 + ((rr & 7) << 4);
        vbV[t] = 8192 + rr * 128 + ((rr & 7) << 4);
    }

    float rsum = 0.f;
    f32x16 oacc[2] = {};

    const int kt0 = half * 16;
    stage(kt0, 0);
    for (int ktl = 0; ktl < 16; ++ktl) {
        const int cb = ktl & 1;
        __syncthreads();
        if (ktl + 1 < 16) stage(kt0 + ktl + 1, cb ^ 1);
        const char* ldsb = smem + cb * 16384;

        // S^T = K @ Q^T
        f32x16 st[2] = {};
        #pragma unroll
        for (int t = 0; t < 2; ++t) {
            #pragma unroll
            for (int c = 0; c < 4; ++c) {
                bf16x8 kf = *reinterpret_cast<const bf16x8*>(ldsb + (vbK[t] ^ (((c << 1) | hh) << 4)));
                st[t] = __builtin_amdgcn_mfma_f32_32x32x16_bf16(kf, qf[c], st[t], 0, 0, 0);
            }
        }

        // P = exp2(S^T); P^T B-frags in-register
        bf16x8 pfrag[4];
        #pragma unroll
        for (int t = 0; t < 2; ++t) {
            float p[16];
            #pragma unroll
            for (int rr = 0; rr < 16; ++rr) {
                p[rr] = __builtin_amdgcn_exp2f(st[t][rr]);
                rsum += p[rr];
            }
            #pragma unroll
            for (int g = 0; g < 2; ++g) {
                float* pg = p + g * 8;
                #pragma unroll
                for (int j = 0; j < 4; ++j)
                    asm volatile("v_permlane32_swap_b32 %0, %1" : "+v"(pg[j]), "+v"(pg[j + 4]));
                u32 pkv[4];
                #pragma unroll
                for (int j = 0; j < 4; ++j) pkv[j] = pk_bf16(pg[2 * j], pg[2 * j + 1]);
                pfrag[t * 2 + g] = *reinterpret_cast<bf16x8*>(pkv);
            }
        }

        // O^T += V^T @ P^T
        #pragma unroll
        for (int t = 0; t < 2; ++t) {
            #pragma unroll
            for (int c = 0; c < 4; ++c) {
                bf16x8 vf = *reinterpret_cast<const bf16x8*>(ldsb + (vbV[t] ^ (((c << 1) | hh) << 4)));
                oacc[t] = __builtin_amdgcn_mfma_f32_32x32x16_bf16(vf, pfrag[c], oacc[t], 0, 0, 0);
            }
        }
    }

    rsum += __shfl_xor(rsum, 32);

    // epilogue: unnormalized O^T -> LDS transpose -> coalesced partial store
    #pragma unroll
    for (int pass = 0; pass < 2; ++pass) {
        __syncthreads();
        if ((wave >> 1) == pass) {
            const int qloc = (wave & 1) * 32 + l31;
            #pragma unroll
            for (int t = 0; t < 2; ++t) {
                #pragma unroll
                for (int rq = 0; rq < 4; ++rq) {
                    const int d0 = t * 32 + rq * 8 + hh * 4;
                    *reinterpret_cast<u32*>(&Os[qloc * 72 + d0]) =
                        pk_bf16(oacc[t][rq * 4 + 0], oacc[t][rq * 4 + 1]);
                    *reinterpret_cast<u32*>(&Os[qloc * 72 + d0 + 2]) =
                        pk_bf16(oacc[t][rq * 4 + 2], oacc[t][rq * 4 + 3]);
                }
            }
        }
        __syncthreads();
        {
            const int row = tid >> 2, cc = (tid & 3) * 16;
            u16* dst = Op + hb + (size_t)(qt * 128 + pass * 64 + row) * DH + cc;
            *reinterpret_cast<uint4*>(dst)     = *reinterpret_cast<const uint4*>(&Os[row * 72 + cc]);
            *reinterpret_cast<uint4*>(dst + 8) = *reinterpret_cast<const uint4*>(&Os[row * 72 + cc + 8]);
        }
    }
    if (hh == 0) rp[((size_t)(b * H + h)) * L + q0 + l31] = rsum;
}

// ---------------------------------------------------------------------------
// attn_merge: ctx[b,l,h*64+d] = (O0+O1) / (r0+r1)
// ---------------------------------------------------------------------------
__global__ __launch_bounds__(256) void attn_merge(
    const u16* __restrict__ O0, const u16* __restrict__ O1,
    const float* __restrict__ r0, const float* __restrict__ r1,
    u16* __restrict__ ctx)
{
    const int g = blockIdx.x * 256 + threadIdx.x;
    const int row = g >> 3, dc = (g & 7) * 8;
    const int b = row >> 15, h = (row >> 11) & (H - 1), l = row & (L - 1);
    const float inv = 1.0f / (r0[row] + r1[row]);
    bf16x8 a = *reinterpret_cast<const bf16x8*>(O0 + (size_t)row * DH + dc);
    bf16x8 c = *reinterpret_cast<const bf16x8*>(O1 + (size_t)row * DH + dc);
    u32 o[4];
    #pragma unroll
    for (int i = 0; i < 4; ++i)
        o[i] = pk_bf16(((float)a[2 * i] + (float)c[2 * i]) * inv,
                       ((float)a[2 * i + 1] + (float)c[2 * i + 1]) * inv);
    *reinterpret_cast<uint4*>(ctx + ((size_t)(b * L + l)) * Dm + h * DH + dc) =
        *reinterpret_cast<uint4*>(o);
}

// ---------------------------------------------------------------------------
// gemm_out: out = ctx(bf16 [M][K]) @ Wot^T + bo -> fp32.  128x64 tiles, dbuf.
// ---------------------------------------------------------------------------
__global__ __launch_bounds__(256) void gemm_out(
    const u16* __restrict__ A, const u16* __restrict__ Bt,
    const float* __restrict__ bias, float* __restrict__ out)
{
    __shared__ u16 As[2][128 * 32];
    __shared__ u16 Bs[2][64 * 32];
    const int tid = threadIdx.x;
    const int wave = tid >> 6, lane = tid & 63;
    const int quad = lane >> 4, l16 = lane & 15;
    const int n0 = blockIdx.x * 64, m0 = blockIdx.y * 128;

    const int srow = lane >> 2;
    const int skc  = (lane & 3) * 8;

    f32x4 acc[2][4] = {};

    auto stage = [&](int k0, int bi) {
        #pragma unroll
        for (int i = 0; i < 2; ++i) {
            const int ra = i * 64 + wave * 16;
            gl2lds16(A + (size_t)(m0 + ra + srow) * Dm + k0 + skc, &As[bi][ra * 32]);
        }
        gl2lds16(Bt + (size_t)(n0 + wave * 16 + srow) * Dm + k0 + skc, &Bs[bi][wave * 16 * 32]);
    };

    stage(0, 0);
    for (int k0 = 0, it = 0; k0 < Dm; k0 += 32, ++it) {
        const int cb = it & 1;
        __syncthreads();
        if (k0 + 32 < Dm) stage(k0 + 32, cb ^ 1);
        bf16x8 af[2], bf[4];
        #pragma unroll
        for (int t = 0; t < 2; ++t)
            af[t] = *reinterpret_cast<const bf16x8*>(&As[cb][(wave * 32 + t * 16 + l16) * 32 + quad * 8]);
        #pragma unroll
        for (int t = 0; t < 4; ++t)
            bf[t] = *reinterpret_cast<const bf16x8*>(&Bs[cb][(t * 16 + l16) * 32 + quad * 8]);
        #pragma unroll
        for (int mt = 0; mt < 2; ++mt)
            #pragma unroll
            for (int nt = 0; nt < 4; ++nt)
                acc[mt][nt] = __builtin_amdgcn_mfma_f32_16x16x32_bf16(af[mt], bf[nt], acc[mt][nt], 0, 0, 0);
    }

    #pragma unroll
    for (int nt = 0; nt < 4; ++nt) {
        const int n = n0 + nt * 16 + l16;
        const float badd = bias[n];
        #pragma unroll
        for (int mt = 0; mt < 2; ++mt) {
            #pragma unroll
            for (int r = 0; r < 4; ++r) {
                const int m = m0 + wave * 32 + mt * 16 + quad * 4 + r;
                out[(size_t)m * Dm + n] = acc[mt][nt][r] + badd;
            }
        }
    }
}

// ---------------------------------------------------------------------------
extern "C" void kernel_launch(void* const* d_in, const int* in_sizes, int n_in,
                              void* d_out, int out_size, void* d_ws, size_t ws_size,
                              hipStream_t stream) {
    const float* q  = (const float*)d_in[0];
    const float* k  = (const float*)d_in[1];
    const float* v  = (const float*)d_in[2];
    const float* Wq = (const float*)d_in[3];
    const float* bq = (const float*)d_in[4];
    const float* Wk = (const float*)d_in[5];
    const float* bk = (const float*)d_in[6];
    const float* Wv = (const float*)d_in[7];
    const float* bv = (const float*)d_in[8];
    const float* Wo = (const float*)d_in[9];
    const float* bo = (const float*)d_in[10];
    float* out = (float*)d_out;

    // ws (u16 elems): Abuf 12M | Wt 4M | Qh 4M | Kh 4M | Vth 4M | O0 4M | O1 4M | rsums 2*64K f32
    u16* Abuf = (u16*)d_ws;
    u16* Wt   = Abuf + 3 * (size_t)M * Dm;
    u16* Qh   = Wt + 4 * (size_t)Dm * Dm;
    u16* Kh   = Qh + PER;
    u16* Vth  = Kh + PER;
    u16* O0   = Vth + PER;
    float* rs = (float*)(O0 + 2 * PER);
    u16* ctx  = Abuf;   // overlay (Abuf dead after gemm_qkv)

    convert_in <<<dim3((M * Dm) / 8 / 256, 3), 256, 0, stream>>>(q, k, v, Abuf);
    convert_wt <<<dim3(Dm / 64, Dm / 64, 4), 256, 0, stream>>>(Wq, Wk, Wv, Wo, Wt);
    gemm_qkv   <<<dim3(Dm / 128, M / 128, 3), 256, 0, stream>>>(Abuf, Wt, bq, bk, bv, Qh, Kh, Vth);
    attn       <<<dim3(L / 128 * 2, H, Bn), 256, 0, stream>>>(Qh, Kh, Vth, O0, rs);
    attn_merge <<<NQ * 8 / 256, 256, 0, stream>>>(O0, O0 + PER, rs, rs + NQ, ctx);
    gemm_out   <<<dim3(Dm / 64, M / 128), 256, 0, stream>>>(ctx, Wt + 3 * (size_t)Dm * Dm, bo, out);
}

// Round 8
// 235.772 us; speedup vs baseline: 1.0118x; 1.0118x over previous
//
#include <hip/hip_runtime.h>
#include <cstdint>
#include <cstddef>

typedef __bf16 bf16x8 __attribute__((ext_vector_type(8)));
typedef float f32x4 __attribute__((ext_vector_type(4)));
typedef float f32x16 __attribute__((ext_vector_type(16)));
typedef unsigned short u16;
typedef unsigned int u32;

static constexpr int Bn = 2;       // batch
static constexpr int L  = 2048;    // sequence
static constexpr int Dm = 1024;    // model dim
static constexpr int H  = 16;      // heads
static constexpr int DH = 64;      // head dim
static constexpr int M  = Bn * L;  // 4096 rows
static constexpr size_t PER = (size_t)Bn * H * L * DH;   // 4M elems
static constexpr int NQ = Bn * H * L;                    // 65536 q rows

#define SC 0.18033688f   /* 0.125 * log2(e): folded into Q so QK^T is in exp2 domain */

__device__ __forceinline__ u16 f2bf(float f) {
    union { float f; u32 u; } v; v.f = f;
    u32 u = v.u + 0x7FFFu + ((v.u >> 16) & 1u);   // RNE
    return (u16)(u >> 16);
}

// packed f32x2 -> bf16x2 (low = a). HW v_cvt_pk_bf16_f32 on gfx950.
__device__ __forceinline__ u32 pk_bf16(float a, float b) {
#if __has_builtin(__builtin_amdgcn_cvt_pk_bf16_f32)
    typedef __bf16 bf16x2_t __attribute__((ext_vector_type(2)));
    bf16x2_t t = __builtin_amdgcn_cvt_pk_bf16_f32(a, b);
    u32 r; __builtin_memcpy(&r, &t, 4); return r;
#else
    return (u32)f2bf(a) | ((u32)f2bf(b) << 16);
#endif
}
__device__ __forceinline__ u16 f2bf1(float f) { return (u16)(pk_bf16(f, f) & 0xffffu); }

// async global->LDS, 16B per lane; LDS dest = wave-uniform base + lane*16
__device__ __forceinline__ void gl2lds16(const void* g, void* l) {
    __builtin_amdgcn_global_load_lds(
        (const __attribute__((address_space(1))) u32*)(uintptr_t)g,
        (__attribute__((address_space(3))) u32*)(uintptr_t)l, 16, 0, 0);
}

// ---------------------------------------------------------------------------
// convert_in: fp32 -> bf16, flat copy of q,k,v (blockIdx.y selects tensor)
// ---------------------------------------------------------------------------
__global__ __launch_bounds__(256) void convert_in(
    const float* __restrict__ q, const float* __restrict__ k, const float* __restrict__ v,
    u16* __restrict__ dst)
{
    const float* src = (blockIdx.y == 0) ? q : (blockIdx.y == 1) ? k : v;
    u16* d = dst + (size_t)blockIdx.y * M * Dm;
    const size_t t = (size_t)blockIdx.x * 256 + threadIdx.x;
    const float4* s4 = reinterpret_cast<const float4*>(src) + t * 2;
    float4 f0 = s4[0], f1 = s4[1];
    u32 o[4] = { pk_bf16(f0.x, f0.y), pk_bf16(f0.z, f0.w),
                 pk_bf16(f1.x, f1.y), pk_bf16(f1.z, f1.w) };
    reinterpret_cast<uint4*>(d)[t] = *reinterpret_cast<uint4*>(o);
}

// ---------------------------------------------------------------------------
// convert_wt: fp32 W [K][N] -> bf16 W^T [N][K], 64x64 LDS tile. z selects W.
// ---------------------------------------------------------------------------
__global__ __launch_bounds__(256) void convert_wt(
    const float* __restrict__ Wq, const float* __restrict__ Wk,
    const float* __restrict__ Wv, const float* __restrict__ Wo,
    u16* __restrict__ dst)
{
    __shared__ u16 Ts[64][72];
    const int z = blockIdx.z;
    const float* W = (z == 0) ? Wq : (z == 1) ? Wk : (z == 2) ? Wv : Wo;
    u16* o = dst + (size_t)z * Dm * Dm;
    const int n0 = blockIdx.x * 64, k0 = blockIdx.y * 64;
    const int tid = threadIdx.x;

    {
        const int kr = tid >> 2, nc = (tid & 3) * 16;
        const float* s = W + (size_t)(k0 + kr) * Dm + n0 + nc;
        const float4* s4 = reinterpret_cast<const float4*>(s);
        float4 a = s4[0], b = s4[1], c = s4[2], d = s4[3];
        u32 t[8] = { pk_bf16(a.x, a.y), pk_bf16(a.z, a.w), pk_bf16(b.x, b.y), pk_bf16(b.z, b.w),
                     pk_bf16(c.x, c.y), pk_bf16(c.z, c.w), pk_bf16(d.x, d.y), pk_bf16(d.z, d.w) };
        *reinterpret_cast<uint4*>(&Ts[kr][nc])     = reinterpret_cast<uint4*>(t)[0];
        *reinterpret_cast<uint4*>(&Ts[kr][nc + 8]) = reinterpret_cast<uint4*>(t)[1];
    }
    __syncthreads();
    {
        const int nr = tid >> 2, kc = (tid & 3) * 16;
        u16 w[16];
        #pragma unroll
        for (int j = 0; j < 16; ++j) w[j] = Ts[kc + j][nr];
        u16* dptr = o + (size_t)(n0 + nr) * Dm + k0 + kc;
        *reinterpret_cast<uint4*>(dptr)     = reinterpret_cast<uint4*>(w)[0];
        *reinterpret_cast<uint4*>(dptr + 8) = reinterpret_cast<uint4*>(w)[1];
    }
}

// ---------------------------------------------------------------------------
// gemm_qkv: 128x128 tile, BK=32, dbuf single-barrier K-loop.
// XCD-aware block remap: assuming block b -> XCD b%8, each XCD's resident set
// covers 4 m-rows x 8 n-cols (A 1MB + B 2MB = 3MB working set per 4MB L2).
// z==2 stages the C tile transposed and stores V^T [B,H,DH,L] directly.
// ---------------------------------------------------------------------------
__global__ __launch_bounds__(256) void gemm_qkv(
    const u16* __restrict__ Abuf, const u16* __restrict__ Wtb,
    const float* __restrict__ bq, const float* __restrict__ bk, const float* __restrict__ bv,
    u16* __restrict__ Qh, u16* __restrict__ Kh, u16* __restrict__ Vth)
{
    __shared__ __align__(16) char smem[36864];   // main: As0/As1 @0/8192, Bs0/Bs1 @16384/24576; epi: 4x9216B

    const int tid = threadIdx.x;
    const int wave = tid >> 6, lane = tid & 63;
    const int quad = lane >> 4, l16 = lane & 15;
    const int wr = wave >> 1, wc = wave & 1;
    const int z = blockIdx.z;
    const u16* A  = Abuf + (size_t)z * M * Dm;
    const u16* Bt = Wtb  + (size_t)z * Dm * Dm;
    const float* bias = (z == 0) ? bq : (z == 1) ? bk : bv;
    u16* out = (z == 0) ? Qh : (z == 1) ? Kh : Vth;

    // XCD-locality remap (bijective on 256): m_idx in 0..31, n_idx in 0..7
    const int bid = blockIdx.y * 8 + blockIdx.x;
    const int m_idx = 4 * (bid & 7) + ((bid >> 3) & 3);
    const int n_idx = bid >> 5;
    const int n0 = n_idx * 128, m0 = m_idx * 128;

    const int srow = lane >> 2;
    const int skc  = (lane & 3) * 8;

    f32x4 acc[4][4] = {};

    auto stage = [&](int k0, int bi) {
        #pragma unroll
        for (int i = 0; i < 2; ++i) {
            const int ra = i * 64 + wave * 16;
            gl2lds16(A  + (size_t)(m0 + ra + srow) * Dm + k0 + skc, smem + bi * 8192 + ra * 64);
            gl2lds16(Bt + (size_t)(n0 + ra + srow) * Dm + k0 + skc, smem + 16384 + bi * 8192 + ra * 64);
        }
    };

    stage(0, 0);
    for (int k0 = 0, it = 0; k0 < Dm; k0 += 32, ++it) {
        const int cb = it & 1;
        __syncthreads();
        if (k0 + 32 < Dm) stage(k0 + 32, cb ^ 1);
        const u16* Asb = (const u16*)(smem + cb * 8192);
        const u16* Bsb = (const u16*)(smem + 16384 + cb * 8192);
        bf16x8 af[4], bf[4];
        #pragma unroll
        for (int t = 0; t < 4; ++t) {
            af[t] = *reinterpret_cast<const bf16x8*>(&Asb[(wr * 64 + t * 16 + l16) * 32 + quad * 8]);
            bf[t] = *reinterpret_cast<const bf16x8*>(&Bsb[(wc * 64 + t * 16 + l16) * 32 + quad * 8]);
        }
        #pragma unroll
        for (int mt = 0; mt < 4; ++mt)
            #pragma unroll
            for (int nt = 0; nt < 4; ++nt)
                acc[mt][nt] = __builtin_amdgcn_mfma_f32_16x16x32_bf16(af[mt], bf[nt], acc[mt][nt], 0, 0, 0);
    }

    // ---- epilogue: C tile -> per-wave LDS [64][72] -> coalesced stores ----
    __syncthreads();   // all main-loop LDS reads done before overlay
    u16* tile = (u16*)smem + wave * 4608;        // 64*72 u16 = 9216B per wave
    const float qscale = (z == 0) ? SC : 1.0f;
    #pragma unroll
    for (int nt = 0; nt < 4; ++nt) {
        const int n = n0 + wc * 64 + nt * 16 + l16;
        const float badd = bias[n];
        const int cc = nt * 16 + l16;
        #pragma unroll
        for (int mt = 0; mt < 4; ++mt) {
            #pragma unroll
            for (int r = 0; r < 4; ++r) {
                const int rr = mt * 16 + quad * 4 + r;
                const u16 vv = f2bf1((acc[mt][nt][r] + badd) * qscale);
                if (z == 2) tile[cc * 72 + rr] = vv;   // transposed: [d][ll]
                else        tile[rr * 72 + cc] = vv;   // [ll][d]
            }
        }
    }
    __syncthreads();

    const int rsub = lane >> 3;          // 0..7
    const int csub = (lane & 7) * 8;     // u16 col offset (16B)
    const int h2 = (n0 + wc * 64) >> 6;
    const int mb = m0 + wr * 64;
    const int bb = mb >> 11, ll0 = mb & 2047;
    if (z == 2) {
        const size_t baseV = ((size_t)(bb * H + h2)) * DH * L;
        #pragma unroll
        for (int j = 0; j < 8; ++j) {
            const int d = j * 8 + rsub;
            uint4 vv = *reinterpret_cast<const uint4*>(&tile[d * 72 + csub]);
            *reinterpret_cast<uint4*>(out + baseV + (size_t)d * L + ll0 + csub) = vv;
        }
    } else {
        const size_t base = ((size_t)(bb * H + h2)) * L * DH;
        #pragma unroll
        for (int j = 0; j < 8; ++j) {
            const int row = j * 8 + rsub;
            uint4 vv = *reinterpret_cast<const uint4*>(&tile[row * 72 + csub]);
            *reinterpret_cast<uint4*>(out + base + (size_t)(ll0 + row) * DH + csub) = vv;
        }
    }
}

// ---------------------------------------------------------------------------
// attn v7: k-split x2 (R7) + VALU diet:
//  - row-sums via ones-MFMA (replaces 32 v_add + final shfl; sums the same
//    rounded P~ the PV MFMA consumes -> self-consistent normalization)
//  - pack-then-swap: cvt to packed bf16 words first, then TWO
//    v_permlane32_swap_b32 on u32 words per 16-key group (was four on f32)
// ---------------------------------------------------------------------------
__global__ __launch_bounds__(256) void attn(
    const u16* __restrict__ Qh, const u16* __restrict__ Kh,
    const u16* __restrict__ Vth, u16* __restrict__ Opart, float* __restrict__ rsums)
{
    __shared__ __align__(16) char smem[32768];   // 2 x (K 8KB + V 8KB); Os overlays buf0
    u16* Os = (u16*)smem;

    const int tid  = threadIdx.x;
    const int wave = tid >> 6, lane = tid & 63;
    const int l31  = lane & 31, hh = lane >> 5;
    const int qt = blockIdx.x >> 1, half = blockIdx.x & 1;
    const int h = blockIdx.y, b = blockIdx.z;
    const size_t hb = ((size_t)(b * H + h)) * L * DH;
    const int q0 = qt * 128 + wave * 32;

    u16*  Op = Opart + (size_t)half * PER;
    float* rp = rsums + (size_t)half * NQ;

    // Q fragments (B operand), in regs
    bf16x8 qf[4];
    {
        const u16* qp = Qh + hb + (size_t)(q0 + l31) * DH + hh * 8;
        #pragma unroll
        for (int c = 0; c < 4; ++c)
            qf[c] = *reinterpret_cast<const bf16x8*>(qp + c * 16);
    }

    // ones A-fragment for the row-sum MFMA
    bf16x8 ones;
    {
        u32 ov[4] = { 0x3F803F80u, 0x3F803F80u, 0x3F803F80u, 0x3F803F80u };
        ones = *reinterpret_cast<bf16x8*>(ov);
    }

    const int r_off = lane >> 3;
    const int s_sl  = lane & 7;

    auto stage = [&](int kt, int bi) {
        char* base = smem + bi * 16384;
        #pragma unroll
        for (int i = 0; i < 2; ++i) {
            const int rr = wave * 16 + i * 8 + r_off;
            gl2lds16(Kh  + hb + (size_t)(kt * 64 + rr) * DH + ((s_sl ^ (rr & 7)) << 3),
                     base + (wave * 16 + i * 8) * 128);
            gl2lds16(Vth + hb + (size_t)rr * L + kt * 64 + ((s_sl ^ (rr & 7)) << 3),
                     base + 8192 + (wave * 16 + i * 8) * 128);
        }
    };

    int vbK[2], vbV[2];
    #pragma unroll
    for (int t = 0; t < 2; ++t) {
        const int rr = t * 32 + l31;
        vbK[t] = rr * 128 + ((rr & 7) << 4);
        vbV[t] = 8192 + rr * 128 + ((rr & 7) << 4);
    }

    f32x16 oacc[2] = {};
    f32x16 oaccR = {};   // row-sum accumulator (all 16 regs equal per lane)

    const int kt0 = half * 16;
    stage(kt0, 0);
    for (int ktl = 0; ktl < 16; ++ktl) {
        const int cb = ktl & 1;
        __syncthreads();
        if (ktl + 1 < 16) stage(kt0 + ktl + 1, cb ^ 1);
        const char* ldsb = smem + cb * 16384;

        // S^T = K @ Q^T
        f32x16 st[2] = {};
        #pragma unroll
        for (int t = 0; t < 2; ++t) {
            #pragma unroll
            for (int c = 0; c < 4; ++c) {
                bf16x8 kf = *reinterpret_cast<const bf16x8*>(ldsb + (vbK[t] ^ (((c << 1) | hh) << 4)));
                st[t] = __builtin_amdgcn_mfma_f32_32x32x16_bf16(kf, qf[c], st[t], 0, 0, 0);
            }
        }

        // P = exp2(S^T); pack to bf16 words, then swap packed words across halves
        bf16x8 pfrag[4];
        #pragma unroll
        for (int t = 0; t < 2; ++t) {
            float p[16];
            #pragma unroll
            for (int rr = 0; rr < 16; ++rr)
                p[rr] = __builtin_amdgcn_exp2f(st[t][rr]);
            #pragma unroll
            for (int g = 0; g < 2; ++g) {
                float* pg = p + g * 8;
                u32 w0 = pk_bf16(pg[0], pg[1]);
                u32 w1 = pk_bf16(pg[2], pg[3]);
                u32 w2 = pk_bf16(pg[4], pg[5]);
                u32 w3 = pk_bf16(pg[6], pg[7]);
                asm volatile("v_permlane32_swap_b32 %0, %1" : "+v"(w0), "+v"(w2));
                asm volatile("v_permlane32_swap_b32 %0, %1" : "+v"(w1), "+v"(w3));
                u32 pkv[4] = { w0, w1, w2, w3 };
                pfrag[t * 2 + g] = *reinterpret_cast<bf16x8*>(pkv);
            }
        }

        // O^T += V^T @ P^T ; row-sums += ones @ P^T
        #pragma unroll
        for (int c = 0; c < 4; ++c) {
            #pragma unroll
            for (int t = 0; t < 2; ++t) {
                bf16x8 vf = *reinterpret_cast<const bf16x8*>(ldsb + (vbV[t] ^ (((c << 1) | hh) << 4)));
                oacc[t] = __builtin_amdgcn_mfma_f32_32x32x16_bf16(vf, pfrag[c], oacc[t], 0, 0, 0);
            }
            oaccR = __builtin_amdgcn_mfma_f32_32x32x16_bf16(ones, pfrag[c], oaccR, 0, 0, 0);
        }
    }

    // epilogue: unnormalized O^T -> LDS transpose -> coalesced partial store
    #pragma unroll
    for (int pass = 0; pass < 2; ++pass) {
        __syncthreads();
        if ((wave >> 1) == pass) {
            const int qloc = (wave & 1) * 32 + l31;
            #pragma unroll
            for (int t = 0; t < 2; ++t) {
                #pragma unroll
                for (int rq = 0; rq < 4; ++rq) {
                    const int d0 = t * 32 + rq * 8 + hh * 4;
                    *reinterpret_cast<u32*>(&Os[qloc * 72 + d0]) =
                        pk_bf16(oacc[t][rq * 4 + 0], oacc[t][rq * 4 + 1]);
                    *reinterpret_cast<u32*>(&Os[qloc * 72 + d0 + 2]) =
                        pk_bf16(oacc[t][rq * 4 + 2], oacc[t][rq * 4 + 3]);
                }
            }
        }
        __syncthreads();
        {
            const int row = tid >> 2, cc = (tid & 3) * 16;
            u16* dst = Op + hb + (size_t)(qt * 128 + pass * 64 + row) * DH + cc;
            *reinterpret_cast<uint4*>(dst)     = *reinterpret_cast<const uint4*>(&Os[row * 72 + cc]);
            *reinterpret_cast<uint4*>(dst + 8) = *reinterpret_cast<const uint4*>(&Os[row * 72 + cc + 8]);
        }
    }
    if (hh == 0) rp[((size_t)(b * H + h)) * L + q0 + l31] = oaccR[0];
}

// ---------------------------------------------------------------------------
// attn_merge: ctx[b,l,h*64+d] = (O0+O1) / (r0+r1)
// ---------------------------------------------------------------------------
__global__ __launch_bounds__(256) void attn_merge(
    const u16* __restrict__ O0, const u16* __restrict__ O1,
    const float* __restrict__ r0, const float* __restrict__ r1,
    u16* __restrict__ ctx)
{
    const int g = blockIdx.x * 256 + threadIdx.x;
    const int row = g >> 3, dc = (g & 7) * 8;
    const int b = row >> 15, h = (row >> 11) & (H - 1), l = row & (L - 1);
    const float inv = 1.0f / (r0[row] + r1[row]);
    bf16x8 a = *reinterpret_cast<const bf16x8*>(O0 + (size_t)row * DH + dc);
    bf16x8 c = *reinterpret_cast<const bf16x8*>(O1 + (size_t)row * DH + dc);
    u32 o[4];
    #pragma unroll
    for (int i = 0; i < 4; ++i)
        o[i] = pk_bf16(((float)a[2 * i] + (float)c[2 * i]) * inv,
                       ((float)a[2 * i + 1] + (float)c[2 * i + 1]) * inv);
    *reinterpret_cast<uint4*>(ctx + ((size_t)(b * L + l)) * Dm + h * DH + dc) =
        *reinterpret_cast<uint4*>(o);
}

// ---------------------------------------------------------------------------
// gemm_out: out = ctx(bf16 [M][K]) @ Wot^T + bo -> fp32.
// 128x128 tile @ 512 threads (8 waves, 4m x 2n of 64x32 each), dbuf K-loop.
// Staging: 1 inst/wave for A + 1 for B per iter (64 FLOP/staged-byte, was 44).
// ---------------------------------------------------------------------------
__global__ __launch_bounds__(512) void gemm_out(
    const u16* __restrict__ A, const u16* __restrict__ Bt,
    const float* __restrict__ bias, float* __restrict__ out)
{
    __shared__ u16 As[2][128 * 32];
    __shared__ u16 Bs[2][128 * 32];
    const int tid = threadIdx.x;
    const int wave = tid >> 6, lane = tid & 63;
    const int quad = lane >> 4, l16 = lane & 15;
    const int wr = wave >> 1, wc = wave & 1;   // wr 0..3 (32-row strip), wc 0..1 (64-col half)
    const int n0 = blockIdx.x * 128, m0 = blockIdx.y * 128;

    const int srow = lane >> 2;
    const int skc  = (lane & 3) * 8;

    f32x4 acc[2][4] = {};

    auto stage = [&](int k0, int bi) {
        gl2lds16(A  + (size_t)(m0 + wave * 16 + srow) * Dm + k0 + skc, &As[bi][(wave * 16) * 32]);
        gl2lds16(Bt + (size_t)(n0 + wave * 16 + srow) * Dm + k0 + skc, &Bs[bi][(wave * 16) * 32]);
    };

    stage(0, 0);
    for (int k0 = 0, it = 0; k0 < Dm; k0 += 32, ++it) {
        const int cb = it & 1;
        __syncthreads();
        if (k0 + 32 < Dm) stage(k0 + 32, cb ^ 1);
        bf16x8 af[2], bf[4];
        #pragma unroll
        for (int t = 0; t < 2; ++t)
            af[t] = *reinterpret_cast<const bf16x8*>(&As[cb][(wr * 32 + t * 16 + l16) * 32 + quad * 8]);
        #pragma unroll
        for (int t = 0; t < 4; ++t)
            bf[t] = *reinterpret_cast<const bf16x8*>(&Bs[cb][(wc * 64 + t * 16 + l16) * 32 + quad * 8]);
        #pragma unroll
        for (int mt = 0; mt < 2; ++mt)
            #pragma unroll
            for (int nt = 0; nt < 4; ++nt)
                acc[mt][nt] = __builtin_amdgcn_mfma_f32_16x16x32_bf16(af[mt], bf[nt], acc[mt][nt], 0, 0, 0);
    }

    #pragma unroll
    for (int nt = 0; nt < 4; ++nt) {
        const int n = n0 + wc * 64 + nt * 16 + l16;
        const float badd = bias[n];
        #pragma unroll
        for (int mt = 0; mt < 2; ++mt) {
            #pragma unroll
            for (int r = 0; r < 4; ++r) {
                const int m = m0 + wr * 32 + mt * 16 + quad * 4 + r;
                out[(size_t)m * Dm + n] = acc[mt][nt][r] + badd;
            }
        }
    }
}

// ---------------------------------------------------------------------------
extern "C" void kernel_launch(void* const* d_in, const int* in_sizes, int n_in,
                              void* d_out, int out_size, void* d_ws, size_t ws_size,
                              hipStream_t stream) {
    const float* q  = (const float*)d_in[0];
    const float* k  = (const float*)d_in[1];
    const float* v  = (const float*)d_in[2];
    const float* Wq = (const float*)d_in[3];
    const float* bq = (const float*)d_in[4];
    const float* Wk = (const float*)d_in[5];
    const float* bk = (const float*)d_in[6];
    const float* Wv = (const float*)d_in[7];
    const float* bv = (const float*)d_in[8];
    const float* Wo = (const float*)d_in[9];
    const float* bo = (const float*)d_in[10];
    float* out = (float*)d_out;

    // ws (u16 elems): Abuf 12M | Wt 4M | Qh 4M | Kh 4M | Vth 4M | O0 4M | O1 4M | rsums 2*64K f32
    u16* Abuf = (u16*)d_ws;
    u16* Wt   = Abuf + 3 * (size_t)M * Dm;
    u16* Qh   = Wt + 4 * (size_t)Dm * Dm;
    u16* Kh   = Qh + PER;
    u16* Vth  = Kh + PER;
    u16* O0   = Vth + PER;
    float* rs = (float*)(O0 + 2 * PER);
    u16* ctx  = Abuf;   // overlay (Abuf dead after gemm_qkv)

    convert_in <<<dim3((M * Dm) / 8 / 256, 3), 256, 0, stream>>>(q, k, v, Abuf);
    convert_wt <<<dim3(Dm / 64, Dm / 64, 4), 256, 0, stream>>>(Wq, Wk, Wv, Wo, Wt);
    gemm_qkv   <<<dim3(Dm / 128, M / 128, 3), 256, 0, stream>>>(Abuf, Wt, bq, bk, bv, Qh, Kh, Vth);
    attn       <<<dim3(L / 128 * 2, H, Bn), 256, 0, stream>>>(Qh, Kh, Vth, O0, rs);
    attn_merge <<<NQ * 8 / 256, 256, 0, stream>>>(O0, O0 + PER, rs, rs + NQ, ctx);
    gemm_out   <<<dim3(Dm / 128, M / 128), 512, 0, stream>>>(ctx, Wt + 3 * (size_t)Dm * Dm, bo, out);
}